// Round 7
// baseline (32.220 us; speedup 1.0000x reference)
//
#include <hip/hip_runtime.h>

#define VCNT 262144           // 64^3
#define NB 2
#define NT 128
#define HWPIX 65536           // 1*256*256
#define LN2 0.69314718055994531f

typedef float f32x2 __attribute__((ext_vector_type(2)));

static __device__ __forceinline__ float fast_exp2(float x) {
#if __has_builtin(__builtin_amdgcn_exp2f)
    return __builtin_amdgcn_exp2f(x);
#else
    float r; asm("v_exp_f32 %0, %1" : "=v"(r) : "v"(x)); return r;
#endif
}
static __device__ __forceinline__ float fast_rsq(float x) {
#if __has_builtin(__builtin_amdgcn_rsqf)
    return __builtin_amdgcn_rsqf(x);
#else
    float r; asm("v_rsq_f32 %0, %1" : "=v"(r) : "v"(x)); return r;
#endif
}
// wave-uniform broadcast from lane `l` (VALU op, no LDS-unit traffic)
static __device__ __forceinline__ float rl_f(float v, int l) {
    return __uint_as_float(__builtin_amdgcn_readlane(__float_as_uint(v), l));
}

// ---------------------------------------------------------------------------
// Kernel 1: partial slice sums, needed slices only. 16 blocks/slice = 4096
// (16 KB/block for load balance; ~37% early-exit, block-uniform).
// ---------------------------------------------------------------------------
__global__ __launch_bounds__(256) void slice_partial_kernel(
    const float* __restrict__ slices, const int* __restrict__ sidx,
    float* __restrict__ partials)
{
    const int s   = blockIdx.x >> 4;   // 0..255
    const int b   = s >> 7;
    const int tsl = s & 127;

    __shared__ int needed;
    if (threadIdx.x == 0) needed = 0;
    __syncthreads();
    if (threadIdx.x < NT && sidx[(b << 7) + threadIdx.x] == tsl) needed = 1;
    __syncthreads();
    if (!needed) return;               // uniform across block

    const int j = blockIdx.x & 15;
    const float4* p = (const float4*)(slices + (size_t)s * HWPIX) + j * 1024;

    const float4 a0 = p[threadIdx.x];
    const float4 a1 = p[256 + threadIdx.x];
    const float4 a2 = p[512 + threadIdx.x];
    const float4 a3 = p[768 + threadIdx.x];
    float acc = ((a0.x + a0.y) + (a0.z + a0.w))
              + ((a1.x + a1.y) + (a1.z + a1.w))
              + ((a2.x + a2.y) + (a2.z + a2.w))
              + ((a3.x + a3.y) + (a3.z + a3.w));

#pragma unroll
    for (int off = 32; off > 0; off >>= 1)
        acc += __shfl_down(acc, off, 64);

    __shared__ float ws[4];
    const int lane = threadIdx.x & 63;
    const int wid  = threadIdx.x >> 6;
    if (lane == 0) ws[wid] = acc;
    __syncthreads();
    if (threadIdx.x == 0)
        partials[blockIdx.x] = (ws[0] + ws[1]) + (ws[2] + ws[3]);
}

// ---------------------------------------------------------------------------
// Kernel 2: voxel reconstruction, LDS-free inner loop.
//  - O(1) LDS-atomic dedup of duplicate slice indices -> compact table of
//    n unique u (~81 of 128) built once in LDS.
//  - table then copied to a REGISTER table distributed across lanes
//    (lane l holds entries l and 64+l; 10 VGPRs). Inner loop broadcasts
//    entry t via v_readlane (VALU) -> zero LDS-unit traffic per iter.
//  - 2 z-consecutive voxels/thread; coords pre-scaled by ln2 so
//    w = exp(1/dist) = exp2(rsq(d2)).
// Grid: NB*VCNT/512 = 1024 blocks x 256 threads (4 waves/SIMD).
// ---------------------------------------------------------------------------
__global__ __launch_bounds__(256) void recon_kernel(
    const float* __restrict__ transforms,
    const int*   __restrict__ sidx,
    const float* __restrict__ partials,
    float*       __restrict__ out)
{
    __shared__ float4 ct[NT];   // LN2*x, LN2*y, LN2*z, k*mean
    __shared__ float  kk[NT];   // k (multiplicity)
    __shared__ int    cnt[NT];
    __shared__ int    wcnt[2];
    __shared__ int    ncnt;

    const int tid  = threadIdx.x;
    const int lane = tid & 63;
    const int wid  = tid >> 6;
    const int b    = blockIdx.x >> 9;                      // 512 blocks/batch

    // ---- dedup prologue (threads 0..127), O(1) via LDS atomics ----
    if (tid < NT) cnt[tid] = 0;
    __syncthreads();
    if (tid < NT) atomicAdd(&cnt[sidx[(b << 7) + tid]], 1);
    __syncthreads();

    const int  k       = (tid < NT) ? cnt[tid] : 0;
    const bool neededf = (k > 0);
    const unsigned long long mask = __ballot(neededf);
    if (tid < NT && lane == 0) wcnt[wid] = (int)__popcll(mask);
    __syncthreads();
    if (neededf) {
        const int pos = (int)__popcll(mask & ((1ull << lane) - 1ull))
                      + (wid ? wcnt[0] : 0);
        const float* tr = transforms + (size_t)((b << 7) + tid) * 6;
        const float4* pp = (const float4*)(partials + (size_t)((b << 7) + tid) * 16);
        const float4 q0 = pp[0], q1 = pp[1], q2 = pp[2], q3 = pp[3];
        float m = ((q0.x + q0.y) + (q0.z + q0.w))
                + ((q1.x + q1.y) + (q1.z + q1.w))
                + ((q2.x + q2.y) + (q2.z + q2.w))
                + ((q3.x + q3.y) + (q3.z + q3.w));
        m *= (1.0f / (float)HWPIX);
        const float fk = (float)k;
        ct[pos] = make_float4(tr[0] * LN2, tr[1] * LN2, tr[2] * LN2, fk * m);
        kk[pos] = fk;
    }
    if (tid == 0) ncnt = wcnt[0] + wcnt[1];
    __syncthreads();
    const int n = __builtin_amdgcn_readfirstlane(ncnt);

    // ---- register table: lane l holds entry l (A) and 64+l (B) ----
    const float4 cA = ct[lane];       // one-time reads (4-way conflict, once)
    const float  kA = kk[lane];
    const float4 cB = ct[64 + lane];  // entries >= n are garbage, never read
    const float  kB = kk[64 + lane];

    // ---- voxel pair ----
    const int v0 = ((blockIdx.x & 511) << 9) + (tid << 1);
    const float fx = (float)(v0 >> 12) * LN2;
    const float fy = (float)((v0 >> 6) & 63) * LN2;
    const float fz = (float)(v0 & 63) * LN2;
    const f32x2 fzp = {fz, fz + LN2};

    f32x2 wsum = {0.0f, 0.0f};
    f32x2 acc  = {0.0f, 0.0f};

    const int nA = (n < 64) ? n : 64;
#pragma unroll 4
    for (int t = 0; t < nA; ++t) {
        const float cx = rl_f(cA.x, t), cy = rl_f(cA.y, t), cz = rl_f(cA.z, t);
        const float cw = rl_f(cA.w, t), ck = rl_f(kA, t);
        const float dx = fx - cx;
        const float dy = fy - cy;
        const float base = fmaf(dy, dy, dx * dx);
        f32x2 dz, d2, w;
        dz.x = fzp.x - cz;            dz.y = fzp.y - cz;
        d2.x = fmaf(dz.x, dz.x, base); d2.y = fmaf(dz.y, dz.y, base);
        w.x = fast_exp2(fast_rsq(d2.x)); // e^(1/dist), coords ln2-scaled
        w.y = fast_exp2(fast_rsq(d2.y));
        wsum.x = fmaf(w.x, ck, wsum.x);  wsum.y = fmaf(w.y, ck, wsum.y);
        acc.x  = fmaf(w.x, cw, acc.x);   acc.y  = fmaf(w.y, cw, acc.y);
    }
#pragma unroll 4
    for (int t = 64; t < n; ++t) {
        const int l = t - 64;
        const float cx = rl_f(cB.x, l), cy = rl_f(cB.y, l), cz = rl_f(cB.z, l);
        const float cw = rl_f(cB.w, l), ck = rl_f(kB, l);
        const float dx = fx - cx;
        const float dy = fy - cy;
        const float base = fmaf(dy, dy, dx * dx);
        f32x2 dz, d2, w;
        dz.x = fzp.x - cz;            dz.y = fzp.y - cz;
        d2.x = fmaf(dz.x, dz.x, base); d2.y = fmaf(dz.y, dz.y, base);
        w.x = fast_exp2(fast_rsq(d2.x));
        w.y = fast_exp2(fast_rsq(d2.y));
        wsum.x = fmaf(w.x, ck, wsum.x);  wsum.y = fmaf(w.y, ck, wsum.y);
        acc.x  = fmaf(w.x, cw, acc.x);   acc.y  = fmaf(w.y, cw, acc.y);
    }

    float2 o;
    o.x = acc.x / wsum.x;
    o.y = acc.y / wsum.y;
    *(float2*)(out + (size_t)b * VCNT + v0) = o;
}

// ---------------------------------------------------------------------------
extern "C" void kernel_launch(void* const* d_in, const int* in_sizes, int n_in,
                              void* d_out, int out_size, void* d_ws, size_t ws_size,
                              hipStream_t stream)
{
    const float* slices     = (const float*)d_in[0];  // (2,128,1,256,256) f32
    const float* transforms = (const float*)d_in[1];  // (2,128,6) f32
    const int*   sidx       = (const int*)d_in[2];    // (2,128) i32
    float* out      = (float*)d_out;                  // (2,1,64,64,64) f32
    float* partials = (float*)d_ws;                   // 4096 floats scratch

    slice_partial_kernel<<<NB * NT * 16, 256, 0, stream>>>(slices, sidx, partials);
    recon_kernel<<<NB * VCNT / 512, 256, 0, stream>>>(transforms, sidx, partials, out);
}